// Round 10
// baseline (489.910 us; speedup 1.0000x reference)
//
#include <hip/hip_runtime.h>
#include <hip/hip_bf16.h>

#define NA 8192
#define NB 8192
#define NE 32768
#define NC 8
#define CHW 2048        // 8*16*16
#define EPW 8           // edges per wave (persistent)
#define CBLK 1024       // conv grid: 1024 blocks * 4 waves * EPW = NE

typedef float  f4     __attribute__((ext_vector_type(4)));
typedef float  f32x4  __attribute__((ext_vector_type(4)));
typedef short  short8 __attribute__((ext_vector_type(8)));

// conv LDS tile: [18 rows][18 cols][8 ci] bf16; 16 B per (row,col) cell.
// Row 0/17, col 0/17 are the zero halo (SAME padding), ci innermost so a
// B-fragment (8 ci at one spatial point) is ONE aligned ds_read_b128.
#define CELLS (18 * 18)          // 324 cells
#define TILE_US (CELLS * 8)      // 2592 ushort = 5184 B per wave tile

static __device__ __forceinline__ unsigned short f2bf(float f) {
    unsigned u = __float_as_uint(f);
    u = (u + 0x7FFFu + ((u >> 16) & 1u)) >> 16;   // RNE bf16
    return (unsigned short)u;
}

// ---------------- CSR build (tiny kernels) ----------------
__global__ __launch_bounds__(256) void zero_two_kernel(int* a, int* b, int n) {
    int i = blockIdx.x * 256 + threadIdx.x;
    if (i < n) { a[i] = 0; b[i] = 0; }
}

__global__ __launch_bounds__(256) void hist_kernel(
    const int* __restrict__ dst, int* __restrict__ cnt, int n) {
    int i = blockIdx.x * 256 + threadIdx.x;
    if (i < n) atomicAdd(&cnt[dst[i]], 1);
}

__global__ __launch_bounds__(256) void scan_kernel(
    const int* __restrict__ cnt, int* __restrict__ row, int* __restrict__ cur, int n) {
    __shared__ int part[256];
    const int t = threadIdx.x;
    const int chunk = (n + 255) / 256;
    const int base = t * chunk;
    int sum = 0;
    for (int j = 0; j < chunk; ++j) { int idx = base + j; if (idx < n) sum += cnt[idx]; }
    part[t] = sum;
    __syncthreads();
    if (t == 0) {
        int run = 0;
        for (int i = 0; i < 256; ++i) { int tmp = part[i]; part[i] = run; run += tmp; }
    }
    __syncthreads();
    int run = part[t];
    for (int j = 0; j < chunk; ++j) {
        int idx = base + j;
        if (idx < n) { row[idx] = run; cur[idx] = run; run += cnt[idx]; }
    }
    if (t == 255) row[n] = run;
}

__global__ __launch_bounds__(256) void scatter_kernel(
    const int* __restrict__ dst, int* __restrict__ cur, int* __restrict__ perm, int n) {
    int i = blockIdx.x * 256 + threadIdx.x;
    if (i < n) { int p = atomicAdd(&cur[dst[i]], 1); perm[p] = i; }
}

// ---------------- Phase A: conv via bf16 MFMA, persistent wave ----------------
// GEMM view per edge: D[16][16] per spatial row-pair, M=(s,co), N=x, K=96:
//   k = (pair=(dy'∈4 x dx∈3)) * 8 + ci, split into 3 MFMA k-steps of 32.
//   A[(s,co)][k] = W[co][ci][dy'-s+1][dx] (0 if ky out of range) — built ONCE.
//   B[k][x]      = ef[ci][2y+dy'][x+dx-1] — one ds_read_b128 per (lane,kstep).
// Wave processes EPW edges; next edge's u,v prefetched into registers so the
// gather latency hides under current edge's MFMA + stores.
__global__ __launch_bounds__(256, 2) void conv_kernel(
    const float* __restrict__ feat_src,   // [Nsrc, 2048]
    const float* __restrict__ feat_dst,   // [Ndst, 2048]
    const float* __restrict__ Wc,         // [8,8,3,3] OIHW
    const float* __restrict__ bias,       // [8]
    const int*   __restrict__ src_idx,    // [E]
    const int*   __restrict__ dst_idx,    // [E]
    float*       __restrict__ Wh_out)     // [E, 2048]
{
    __shared__ unsigned short lds[4 * TILE_US];   // 20.7 KB / block
    const int tid  = threadIdx.x;
    const int lane = tid & 63;
    const int widx = tid >> 6;
    unsigned short* tp = &lds[widx * TILE_US];

    const int ebase = (blockIdx.x * 4 + widx) * EPW;

    const int g = lane >> 4;      // lane group 0..3 (k-chunk)
    const int x = lane & 15;      // A-row index m / B-col index x / D-col

    // ---- per-wave setup (amortized over EPW edges) ----
    short8 aF[3];
    #pragma unroll
    for (int K = 0; K < 3; ++K) {
        #pragma unroll
        for (int j = 0; j < 8; ++j) {
            const int k    = K * 32 + g * 8 + j;
            const int pair = k >> 3;              // K*4 + g
            const int dy   = pair / 3 - 1;        // -1..2
            const int dx   = pair % 3;            // 0..2
            const int ci   = k & 7;
            const int m    = x;                   // A row
            const int sd   = m >> 3;              // output-row parity
            const int co   = m & 7;
            const int ky   = dy - sd + 1;
            float w = (ky >= 0 && ky <= 2) ? Wc[((co * 8 + ci) * 3 + ky) * 3 + dx] : 0.0f;
            aF[K][j] = (short)f2bf(w);
        }
    }
    int boff[3];
    #pragma unroll
    for (int K = 0; K < 3; ++K) {
        const int pair = K * 4 + g;
        const int dy   = pair / 3 - 1;
        const int dx   = pair % 3;
        boff[K] = (dy + 1) * 18 + (x + dx);
    }
    f32x4 cb;
    #pragma unroll
    for (int j = 0; j < 4; ++j) cb[j] = bias[(g * 4 + j) & 7];

    // zero tile once (halo ring persists; interior overwritten every edge)
    const f4 z4 = {0.f, 0.f, 0.f, 0.f};
    #pragma unroll
    for (int i = 0; i < 6; ++i) {
        int c = lane + 64 * i;
        if (c < CELLS) *(f4*)&tp[c * 8] = z4;
    }

    const int sy = lane >> 2;          // 0..15
    const int sx = (lane & 3) * 4;     // 0,4,8,12

    // ---- prologue: prefetch edge ebase ----
    f4 pu[8], pv[8];
    {
        const int s0 = src_idx[ebase];
        const int d0 = dst_idx[ebase];
        const f4* up = (const f4*)(feat_src + (size_t)s0 * CHW);
        const f4* vp = (const f4*)(feat_dst + (size_t)d0 * CHW);
        #pragma unroll
        for (int ci = 0; ci < 8; ++ci) { pu[ci] = up[lane + 64 * ci]; pv[ci] = vp[lane + 64 * ci]; }
    }

    for (int k = 0; k < EPW; ++k) {
        const int e = ebase + k;

        // ---- stage ef = bf16(u+v) from prefetched regs ----
        short8 pk[4];
        #pragma unroll
        for (int ci = 0; ci < 8; ++ci) {
            f4 ef = pu[ci] + pv[ci];
            pk[0][ci] = (short)f2bf(ef.x);
            pk[1][ci] = (short)f2bf(ef.y);
            pk[2][ci] = (short)f2bf(ef.z);
            pk[3][ci] = (short)f2bf(ef.w);
        }
        #pragma unroll
        for (int m = 0; m < 4; ++m) {
            const int cell = (sy + 1) * 18 + (sx + 1 + m);
            *(short8*)&tp[cell * 8] = pk[m];       // ds_write_b128
        }

        // ---- prefetch next edge's u,v (in flight during MFMA + stores) ----
        if (k + 1 < EPW) {
            const int sN = src_idx[e + 1];
            const int dN = dst_idx[e + 1];
            const f4* up = (const f4*)(feat_src + (size_t)sN * CHW);
            const f4* vp = (const f4*)(feat_dst + (size_t)dN * CHW);
            #pragma unroll
            for (int ci = 0; ci < 8; ++ci) { pu[ci] = up[lane + 64 * ci]; pv[ci] = vp[lane + 64 * ci]; }
        }

        // ---- 8 row-pair MFMA triplets + nontemporal stores ----
        float* whp = Wh_out + (size_t)e * CHW;
        #pragma unroll
        for (int y = 0; y < 8; ++y) {
            f32x4 acc = cb;
            #pragma unroll
            for (int K = 0; K < 3; ++K) {
                short8 b = *(const short8*)&tp[(36 * y + boff[K]) * 8];  // ds_read_b128
                acc = __builtin_amdgcn_mfma_f32_16x16x32_bf16(aF[K], b, acc, 0, 0, 0);
            }
            #pragma unroll
            for (int j = 0; j < 4; ++j) {
                const int m  = g * 4 + j;              // D row = (lane>>4)*4 + reg
                const int sd = m >> 3, co = m & 7;
                __builtin_nontemporal_store(acc[j], &whp[co * 256 + (2 * y + sd) * 16 + x]);
            }
        }
        // wave-private tile: WAR on next iter's ds_write handled by wave program order
    }
}

// ---------------- Phase B: segment mean, one WAVE per dst node ----------------
__global__ __launch_bounds__(256) void mean_kernel(
    const float* __restrict__ Wh,         // [E, 2048]
    const float* __restrict__ feat_src,   // [Nsrc, 2048]
    const int*   __restrict__ src_idx,    // [E]
    const int*   __restrict__ row,        // [Ndst+1]
    const int*   __restrict__ perm,       // [E] edge ids grouped by dst
    float*       __restrict__ h_out,      // [Ndst, 2048]
    int n_nodes)
{
    const int tid  = threadIdx.x;
    const int lane = tid & 63;
    const int n    = blockIdx.x * 4 + (tid >> 6);
    if (n >= n_nodes) return;
    const int beg = row[n], end = row[n + 1];

    f4 acc[8];
    #pragma unroll
    for (int k = 0; k < 8; ++k) { f4 z = {0.f, 0.f, 0.f, 0.f}; acc[k] = z; }

    for (int i = beg; i < end; ++i) {
        const int e = perm[i];
        const int sidx = src_idx[e];
        const f4* wp = (const f4*)(Wh + (size_t)e * CHW);
        const f4* up = (const f4*)(feat_src + (size_t)sidx * CHW);
        #pragma unroll
        for (int k = 0; k < 8; ++k) {
            int i4 = lane + 64 * k;
            f4 a = __builtin_nontemporal_load(&wp[i4]);   // Wh read once
            acc[k] += a + up[i4];                          // u served by L2/L3
        }
    }

    const float inv = end > beg ? 1.0f / (float)(end - beg) : 0.0f;
    float* hp = h_out + (size_t)n * CHW;
    #pragma unroll
    for (int k = 0; k < 8; ++k) {
        f4 o = acc[k] * inv;
        __builtin_nontemporal_store(o, (f4*)&hp[(lane + 64 * k) * 4]);
    }
}

extern "C" void kernel_launch(void* const* d_in, const int* in_sizes, int n_in,
                              void* d_out, int out_size, void* d_ws, size_t ws_size,
                              hipStream_t stream) {
    const float* feat_a = (const float*)d_in[0];
    const float* feat_b = (const float*)d_in[1];
    const float* W_e1   = (const float*)d_in[2];
    const float* b_e1   = (const float*)d_in[3];
    const float* W_e2   = (const float*)d_in[4];
    const float* b_e2   = (const float*)d_in[5];
    const int*   src_e1 = (const int*)d_in[6];
    const int*   dst_e1 = (const int*)d_in[7];
    const int*   src_e2 = (const int*)d_in[8];
    const int*   dst_e2 = (const int*)d_in[9];

    float* out = (float*)d_out;
    float* h_a = out;                                  // [NA, 2048]
    float* h_b = out + (size_t)NA * CHW;               // [NB, 2048]
    float* Wh1 = out + (size_t)(NA + NB) * CHW;        // [E, 2048]
    float* Wh2 = Wh1 + (size_t)NE * CHW;               // [E, 2048]

    // workspace: CSR for both etypes
    int* ws    = (int*)d_ws;
    int* cnt1  = ws;                  // [NB]
    int* row1  = cnt1 + NB;           // [NB+1]
    int* cur1  = row1 + NB + 1;       // [NB]
    int* perm1 = cur1 + NB;           // [NE]
    int* cnt2  = perm1 + NE;          // [NA]
    int* row2  = cnt2 + NA;           // [NA+1]
    int* cur2  = row2 + NA + 1;       // [NA]
    int* perm2 = cur2 + NA;           // [NE]

    // CSR build
    zero_two_kernel<<<(NB + 255) / 256, 256, 0, stream>>>(cnt1, cnt2, NB);
    hist_kernel<<<(NE + 255) / 256, 256, 0, stream>>>(dst_e1, cnt1, NE);
    hist_kernel<<<(NE + 255) / 256, 256, 0, stream>>>(dst_e2, cnt2, NE);
    scan_kernel<<<1, 256, 0, stream>>>(cnt1, row1, cur1, NB);
    scan_kernel<<<1, 256, 0, stream>>>(cnt2, row2, cur2, NA);
    scatter_kernel<<<(NE + 255) / 256, 256, 0, stream>>>(dst_e1, cur1, perm1, NE);
    scatter_kernel<<<(NE + 255) / 256, 256, 0, stream>>>(dst_e2, cur2, perm2, NE);

    // Phase A: conv (MFMA, persistent waves)
    conv_kernel<<<CBLK, 256, 0, stream>>>(feat_a, feat_b, W_e1, b_e1,
                                          src_e1, dst_e1, Wh1);
    conv_kernel<<<CBLK, 256, 0, stream>>>(feat_b, feat_a, W_e2, b_e2,
                                          src_e2, dst_e2, Wh2);

    // Phase B: segment mean (wave per node); h fully overwritten -> no zeroing
    mean_kernel<<<NB / 4, 256, 0, stream>>>(Wh1, feat_a, src_e1, row1, perm1, h_b, NB);
    mean_kernel<<<NA / 4, 256, 0, stream>>>(Wh2, feat_b, src_e2, row2, perm2, h_a, NA);
}

// Round 11
// 419.175 us; speedup vs baseline: 1.1687x; 1.1687x over previous
//
#include <hip/hip_runtime.h>
#include <hip/hip_bf16.h>

#define NA 8192
#define NB 8192
#define NE 32768
#define NC 8
#define CHW 2048        // 8*16*16

typedef float          f4     __attribute__((ext_vector_type(4)));
typedef float          f32x4  __attribute__((ext_vector_type(4)));
typedef short          short8 __attribute__((ext_vector_type(8)));
typedef unsigned short ush4   __attribute__((ext_vector_type(4)));
typedef unsigned short ush8   __attribute__((ext_vector_type(8)));

// conv LDS tile: [18 rows][18 cols][8 ci] bf16; 16 B per (row,col) cell.
// Rows/cols 0 and 17 are the zero halo; ci innermost so one spatial point's
// 8-ci fragment is ONE aligned ds_read_b128.
#define CELLS (18 * 18)
#define TILE_US (CELLS * 8)      // 2592 ushort = 5184 B per wave tile

static __device__ __forceinline__ unsigned short f2bf(float f) {
    unsigned u = __float_as_uint(f);
    u = (u + 0x7FFFu + ((u >> 16) & 1u)) >> 16;   // RNE bf16
    return (unsigned short)u;
}

// ---------------- CSR build ----------------
__global__ __launch_bounds__(256) void zero_two_kernel(int* a, int* b, int n) {
    int i = blockIdx.x * 256 + threadIdx.x;
    if (i < n) { a[i] = 0; b[i] = 0; }
}

__global__ __launch_bounds__(256) void hist_kernel(
    const int* __restrict__ dst1, const int* __restrict__ dst2,
    int* __restrict__ cnt1, int* __restrict__ cnt2) {
    int i = blockIdx.x * 256 + threadIdx.x;   // grid covers 2*NE
    if (i < NE) atomicAdd(&cnt1[dst1[i]], 1);
    else        atomicAdd(&cnt2[dst2[i - NE]], 1);
}

// 2 blocks: block 0 -> etype1 CSR, block 1 -> etype2
__global__ __launch_bounds__(256) void scan_kernel(
    const int* __restrict__ cnt1, int* __restrict__ row1, int* __restrict__ cur1,
    const int* __restrict__ cnt2, int* __restrict__ row2, int* __restrict__ cur2) {
    const int n = 8192;
    const int* cnt = blockIdx.x ? cnt2 : cnt1;
    int* row = blockIdx.x ? row2 : row1;
    int* cur = blockIdx.x ? cur2 : cur1;
    __shared__ int part[256];
    const int t = threadIdx.x;
    const int chunk = n / 256;                // 32
    const int base = t * chunk;
    int sum = 0;
    for (int j = 0; j < chunk; ++j) sum += cnt[base + j];
    part[t] = sum;
    __syncthreads();
    if (t == 0) {
        int run = 0;
        for (int i = 0; i < 256; ++i) { int tmp = part[i]; part[i] = run; run += tmp; }
    }
    __syncthreads();
    int run = part[t];
    for (int j = 0; j < chunk; ++j) {
        row[base + j] = run; cur[base + j] = run; run += cnt[base + j];
    }
    if (t == 255) row[n] = run;
}

__global__ __launch_bounds__(256) void scatter_kernel(
    const int* __restrict__ dst1, const int* __restrict__ dst2,
    int* __restrict__ cur1, int* __restrict__ cur2,
    int* __restrict__ pos1, int* __restrict__ pos2) {
    int i = blockIdx.x * 256 + threadIdx.x;   // grid covers 2*NE
    if (i < NE)  pos1[i]      = atomicAdd(&cur1[dst1[i]], 1);
    else         pos2[i - NE] = atomicAdd(&cur2[dst2[i - NE]], 1);
}

// ---------------- weight-fragment prep (per etype, per lane; built once) ----------------
// B-operand fragment: col n = lane&15 = (sd,co); k = (lane>>4)*8 + j per k-step.
__global__ __launch_bounds__(64) void wprep_kernel(
    const float* __restrict__ W1, const float* __restrict__ W2,
    short8* __restrict__ wfrag)           // [2][64][3]
{
    const float* Wc = blockIdx.x ? W2 : W1;
    const int lane = threadIdx.x;
    const int nn = lane & 15;
    const int sd = nn >> 3, co = nn & 7;
    #pragma unroll
    for (int K = 0; K < 3; ++K) {
        short8 frag;
        #pragma unroll
        for (int j = 0; j < 8; ++j) {
            const int k    = K * 32 + (lane >> 4) * 8 + j;
            const int pair = k >> 3;
            const int dy   = pair / 3 - 1;
            const int dx   = pair % 3;
            const int ci   = k & 7;
            const int ky   = dy - sd + 1;
            float w = (ky >= 0 && ky <= 2) ? Wc[((co * 8 + ci) * 3 + ky) * 3 + dx] : 0.0f;
            frag[j] = (short)f2bf(w);
        }
        wfrag[((size_t)blockIdx.x * 64 + lane) * 3 + K] = frag;
    }
}

// ---------------- Phase A: conv via bf16 MFMA, one WAVE per edge, both etypes ----------------
// Swapped-operand GEMM per edge & row-pair y: D[x][m] (m=(sd,co)), K=96.
//   A (LDS)  : ef patch fragments — row x = lane&15, k=(lane>>4)*8+elem -> ds_read_b128
//   B (regs) : weight fragments (from wprep)  — col m = lane&15, same k layout
//   D        : col m = lane&15, rows x = (lane>>4)*4 + j  -> f4 stores (4 consecutive x)
// Also writes m_e = bf16(u + Wh) into ws at CSR slot pos[e] (mean reads it streaming).
__global__ __launch_bounds__(256, 4) void conv_kernel(
    const float* __restrict__ fa, const float* __restrict__ fb,
    const float* __restrict__ bias1, const float* __restrict__ bias2,
    const int* __restrict__ src1, const int* __restrict__ dst1,
    const int* __restrict__ src2, const int* __restrict__ dst2,
    const int* __restrict__ pos1, const int* __restrict__ pos2,
    const short8* __restrict__ wfrag,     // [2][64][3]
    float* __restrict__ Wh1, float* __restrict__ Wh2,
    unsigned short* __restrict__ m1, unsigned short* __restrict__ m2)
{
    __shared__ unsigned short lds[4 * TILE_US];   // 20.7 KB
    const int tid  = threadIdx.x;
    const int lane = tid & 63;
    const int widx = tid >> 6;
    unsigned short* tp = &lds[widx * TILE_US];

    const int gw  = blockIdx.x * 4 + widx;        // 0 .. 2*NE-1
    const int et2 = gw >= NE;
    const int e   = et2 ? gw - NE : gw;

    const float* feat_src = et2 ? fb : fa;
    const float* feat_dst = et2 ? fa : fb;
    const int s  = __builtin_amdgcn_readfirstlane((et2 ? src2 : src1)[e]);
    const int d  = __builtin_amdgcn_readfirstlane((et2 ? dst2 : dst1)[e]);
    const int pe = __builtin_amdgcn_readfirstlane((et2 ? pos2 : pos1)[e]);

    const int g = lane >> 4;
    const int x = lane & 15;

    // weight fragments (L2-hot) + bias + A-read offsets
    short8 bF[3];
    #pragma unroll
    for (int K = 0; K < 3; ++K) bF[K] = wfrag[((size_t)(et2 ? 64 : 0) + lane) * 3 + K];
    int boff[3];
    #pragma unroll
    for (int K = 0; K < 3; ++K) {
        const int pair = K * 4 + g;
        const int dy   = pair / 3 - 1;
        const int dx   = pair % 3;
        boff[K] = (dy + 1) * 18 + (x + dx);
    }
    const float bv = (et2 ? bias2 : bias1)[x & 7];
    f32x4 cb = {bv, bv, bv, bv};

    // zero tile (halo)
    const f4 z4 = {0.f, 0.f, 0.f, 0.f};
    #pragma unroll
    for (int i = 0; i < 6; ++i) {
        int c = lane + 64 * i;
        if (c < CELLS) *(f4*)&tp[c * 8] = z4;
    }

    // stage ef = bf16(u+v): lane owns cell row (sy+1), cols sx+1..sx+4
    {
        const int sy = lane >> 2;
        const int sx = (lane & 3) * 4;
        const f4* up = (const f4*)(feat_src + (size_t)s * CHW);
        const f4* vp = (const f4*)(feat_dst + (size_t)d * CHW);
        short8 pk[4];
        #pragma unroll
        for (int ci = 0; ci < 8; ++ci) {
            f4 ef = up[lane + 64 * ci] + vp[lane + 64 * ci];
            pk[0][ci] = (short)f2bf(ef.x);
            pk[1][ci] = (short)f2bf(ef.y);
            pk[2][ci] = (short)f2bf(ef.z);
            pk[3][ci] = (short)f2bf(ef.w);
        }
        #pragma unroll
        for (int mm = 0; mm < 4; ++mm) {
            const int cell = (sy + 1) * 18 + (sx + 1 + mm);
            *(short8*)&tp[cell * 8] = pk[mm];       // ds_write_b128
        }
    }
    // wave-private tile: program order + lgkmcnt suffice, no barrier

    const int co = x & 7, sd = x >> 3, xs = g * 4;
    float*          whp = (et2 ? Wh2 : Wh1) + (size_t)e * CHW;
    unsigned short* mp  = (et2 ? m2 : m1) + (size_t)pe * CHW;
    const float*    u2  = feat_src + (size_t)s * CHW;

    #pragma unroll
    for (int y = 0; y < 8; ++y) {
        f32x4 acc = cb;
        #pragma unroll
        for (int K = 0; K < 3; ++K) {
            short8 a8 = *(const short8*)&tp[(36 * y + boff[K]) * 8];  // ds_read_b128
            acc = __builtin_amdgcn_mfma_f32_16x16x32_bf16(a8, bF[K], acc, 0, 0, 0);
        }
        const int off = co * 256 + (2 * y + sd) * 16 + xs;
        f4 w4 = {acc[0], acc[1], acc[2], acc[3]};
        __builtin_nontemporal_store(w4, (f4*)&whp[off]);   // Wh streamed
        f4 u4 = *(const f4*)&u2[off];                      // L1-hot (row just read)
        f4 mv = u4 + w4;
        ush4 m4 = {f2bf(mv.x), f2bf(mv.y), f2bf(mv.z), f2bf(mv.w)};
        *(ush4*)&mp[off] = m4;                             // plain store -> L2/L3 for mean
    }
}

// ---------------- Phase B: segment mean, one WAVE per node, both etypes ----------------
// Reads the CSR-ordered bf16 m runs (contiguous streaming), writes h once.
__global__ __launch_bounds__(256) void mean_kernel(
    const unsigned short* __restrict__ m1, const unsigned short* __restrict__ m2,
    const int* __restrict__ row1, const int* __restrict__ row2,
    float* __restrict__ h_b, float* __restrict__ h_a)
{
    const int tid  = threadIdx.x;
    const int lane = tid & 63;
    const int gw   = blockIdx.x * 4 + (tid >> 6);   // 0 .. NB+NA-1
    const int et2  = gw >= NB;
    const int n    = et2 ? gw - NB : gw;

    const unsigned short* mb = et2 ? m2 : m1;
    const int* row = et2 ? row2 : row1;
    float* hp = (et2 ? h_a : h_b) + (size_t)n * CHW;

    const int beg = row[n], end = row[n + 1];

    float acc[32];
    #pragma unroll
    for (int j = 0; j < 32; ++j) acc[j] = 0.0f;

    for (int i = beg; i < end; ++i) {
        const ush8* mpr = (const ush8*)(mb + (size_t)i * CHW);
        #pragma unroll
        for (int q = 0; q < 4; ++q) {
            ush8 v = __builtin_nontemporal_load(&mpr[lane + 64 * q]);
            #pragma unroll
            for (int j = 0; j < 8; ++j)
                acc[q * 8 + j] += __uint_as_float(((unsigned)v[j]) << 16);
        }
    }

    const float inv = end > beg ? 1.0f / (float)(end - beg) : 0.0f;
    #pragma unroll
    for (int q = 0; q < 4; ++q) {
        const int base = (lane + 64 * q) * 8;
        f4 o0 = {acc[q*8+0] * inv, acc[q*8+1] * inv, acc[q*8+2] * inv, acc[q*8+3] * inv};
        f4 o1 = {acc[q*8+4] * inv, acc[q*8+5] * inv, acc[q*8+6] * inv, acc[q*8+7] * inv};
        __builtin_nontemporal_store(o0, (f4*)&hp[base]);
        __builtin_nontemporal_store(o1, (f4*)&hp[base + 4]);
    }
}

extern "C" void kernel_launch(void* const* d_in, const int* in_sizes, int n_in,
                              void* d_out, int out_size, void* d_ws, size_t ws_size,
                              hipStream_t stream) {
    const float* feat_a = (const float*)d_in[0];
    const float* feat_b = (const float*)d_in[1];
    const float* W_e1   = (const float*)d_in[2];
    const float* b_e1   = (const float*)d_in[3];
    const float* W_e2   = (const float*)d_in[4];
    const float* b_e2   = (const float*)d_in[5];
    const int*   src_e1 = (const int*)d_in[6];
    const int*   dst_e1 = (const int*)d_in[7];
    const int*   src_e2 = (const int*)d_in[8];
    const int*   dst_e2 = (const int*)d_in[9];

    float* out = (float*)d_out;
    float* h_a = out;                                  // [NA, 2048]
    float* h_b = out + (size_t)NA * CHW;               // [NB, 2048]
    float* Wh1 = out + (size_t)(NA + NB) * CHW;        // [E, 2048]
    float* Wh2 = Wh1 + (size_t)NE * CHW;               // [E, 2048]

    // ---- workspace layout ----
    int* ws    = (int*)d_ws;
    int* cnt1  = ws;                  // [8192]
    int* row1  = cnt1 + NB;           // [8193]
    int* cur1  = row1 + NB + 1;       // [8192]
    int* pos1  = cur1 + NB;           // [NE]
    int* cnt2  = pos1 + NE;           // [8192]
    int* row2  = cnt2 + NA;           // [8193]
    int* cur2  = row2 + NA + 1;       // [8192]
    int* pos2  = cur2 + NA;           // [NE]
    short8* wfrag = (short8*)((char*)d_ws + (512 << 10));            // [2][64][3]
    unsigned short* m1 = (unsigned short*)((char*)d_ws + (1 << 20)); // [NE][2048] bf16
    unsigned short* m2 = m1 + (size_t)NE * CHW;                      // [NE][2048] bf16

    // CSR build + weight prep
    zero_two_kernel<<<32, 256, 0, stream>>>(cnt1, cnt2, 8192);
    hist_kernel<<<(2 * NE) / 256, 256, 0, stream>>>(dst_e1, dst_e2, cnt1, cnt2);
    scan_kernel<<<2, 256, 0, stream>>>(cnt1, row1, cur1, cnt2, row2, cur2);
    scatter_kernel<<<(2 * NE) / 256, 256, 0, stream>>>(dst_e1, dst_e2, cur1, cur2, pos1, pos2);
    wprep_kernel<<<2, 64, 0, stream>>>(W_e1, W_e2, wfrag);

    // Phase A: conv for BOTH etypes in one dispatch (wave per edge)
    conv_kernel<<<(2 * NE) / 4, 256, 0, stream>>>(
        feat_a, feat_b, b_e1, b_e2,
        src_e1, dst_e1, src_e2, dst_e2,
        pos1, pos2, wfrag, Wh1, Wh2, m1, m2);

    // Phase B: segment mean for both etypes (wave per node)
    mean_kernel<<<(NB + NA) / 4, 256, 0, stream>>>(m1, m2, row1, row2, h_b, h_a);
}

// Round 12
// 323.068 us; speedup vs baseline: 1.5164x; 1.2975x over previous
//
#include <hip/hip_runtime.h>
#include <hip/hip_bf16.h>

#define NA 8192
#define NB 8192
#define NE 32768
#define NC 8
#define CHW 2048        // 8*16*16

typedef float          f4     __attribute__((ext_vector_type(4)));
typedef float          f32x4  __attribute__((ext_vector_type(4)));
typedef short          short8 __attribute__((ext_vector_type(8)));
typedef unsigned short ush4   __attribute__((ext_vector_type(4)));
typedef unsigned short ush8   __attribute__((ext_vector_type(8)));

// conv LDS tile: [18 rows][18 cols][8 ci] bf16; 16 B per (row,col) cell.
// Rows/cols 0 and 17 are the zero halo; ci innermost so one spatial point's
// 8-ci fragment is ONE aligned ds_read_b128.
#define CELLS (18 * 18)
#define TILE_US (CELLS * 8)      // 2592 ushort = 5184 B per wave tile

static __device__ __forceinline__ unsigned short f2bf(float f) {
    __hip_bfloat16 h = __float2bfloat16(f);      // native RNE cvt (let compiler lower)
    return __builtin_bit_cast(unsigned short, h);
}
static __device__ __forceinline__ float bf2f(unsigned short u) {
    return __uint_as_float(((unsigned)u) << 16);
}

// ---------------- bf16 prepack of both feature arrays (once) ----------------
__global__ __launch_bounds__(256) void pack_kernel(
    const float* __restrict__ fa, const float* __restrict__ fb,
    unsigned short* __restrict__ ga, unsigned short* __restrict__ gb)
{
    const size_t n4 = (size_t)NA * CHW / 4;      // per array (NA == NB)
    size_t stride = (size_t)gridDim.x * 256;
    for (size_t i = (size_t)blockIdx.x * 256 + threadIdx.x; i < n4; i += stride) {
        f4 va = ((const f4*)fa)[i];
        f4 vb = ((const f4*)fb)[i];
        ush4 oa = {f2bf(va.x), f2bf(va.y), f2bf(va.z), f2bf(va.w)};
        ush4 ob = {f2bf(vb.x), f2bf(vb.y), f2bf(vb.z), f2bf(vb.w)};
        ((ush4*)ga)[i] = oa;
        ((ush4*)gb)[i] = ob;
    }
}

// ---------------- CSR build ----------------
__global__ __launch_bounds__(256) void zero_two_kernel(int* a, int* b, int n) {
    int i = blockIdx.x * 256 + threadIdx.x;
    if (i < n) { a[i] = 0; b[i] = 0; }
}

__global__ __launch_bounds__(256) void hist_kernel(
    const int* __restrict__ dst1, const int* __restrict__ dst2,
    int* __restrict__ cnt1, int* __restrict__ cnt2) {
    int i = blockIdx.x * 256 + threadIdx.x;   // grid covers 2*NE
    if (i < NE) atomicAdd(&cnt1[dst1[i]], 1);
    else        atomicAdd(&cnt2[dst2[i - NE]], 1);
}

// 2 blocks: block 0 -> etype1 CSR, block 1 -> etype2
__global__ __launch_bounds__(256) void scan_kernel(
    const int* __restrict__ cnt1, int* __restrict__ row1, int* __restrict__ cur1,
    const int* __restrict__ cnt2, int* __restrict__ row2, int* __restrict__ cur2) {
    const int n = 8192;
    const int* cnt = blockIdx.x ? cnt2 : cnt1;
    int* row = blockIdx.x ? row2 : row1;
    int* cur = blockIdx.x ? cur2 : cur1;
    __shared__ int part[256];
    const int t = threadIdx.x;
    const int chunk = n / 256;                // 32
    const int base = t * chunk;
    int sum = 0;
    for (int j = 0; j < chunk; ++j) sum += cnt[base + j];
    part[t] = sum;
    __syncthreads();
    if (t == 0) {
        int run = 0;
        for (int i = 0; i < 256; ++i) { int tmp = part[i]; part[i] = run; run += tmp; }
    }
    __syncthreads();
    int run = part[t];
    for (int j = 0; j < chunk; ++j) {
        row[base + j] = run; cur[base + j] = run; run += cnt[base + j];
    }
    if (t == 255) row[n] = run;
}

__global__ __launch_bounds__(256) void scatter_kernel(
    const int* __restrict__ dst1, const int* __restrict__ dst2,
    int* __restrict__ cur1, int* __restrict__ cur2,
    int* __restrict__ pos1, int* __restrict__ pos2) {
    int i = blockIdx.x * 256 + threadIdx.x;   // grid covers 2*NE
    if (i < NE)  pos1[i]      = atomicAdd(&cur1[dst1[i]], 1);
    else         pos2[i - NE] = atomicAdd(&cur2[dst2[i - NE]], 1);
}

// ---------------- weight-fragment prep (per etype, per lane; built once) ----------------
__global__ __launch_bounds__(64) void wprep_kernel(
    const float* __restrict__ W1, const float* __restrict__ W2,
    short8* __restrict__ wfrag)           // [2][64][3]
{
    const float* Wc = blockIdx.x ? W2 : W1;
    const int lane = threadIdx.x;
    const int nn = lane & 15;
    const int sd = nn >> 3, co = nn & 7;
    #pragma unroll
    for (int K = 0; K < 3; ++K) {
        short8 frag;
        #pragma unroll
        for (int j = 0; j < 8; ++j) {
            const int k    = K * 32 + (lane >> 4) * 8 + j;
            const int pair = k >> 3;
            const int dy   = pair / 3 - 1;
            const int dx   = pair % 3;
            const int ci   = k & 7;
            const int ky   = dy - sd + 1;
            float w = (ky >= 0 && ky <= 2) ? Wc[((co * 8 + ci) * 3 + ky) * 3 + dx] : 0.0f;
            frag[j] = (short)f2bf(w);
        }
        wfrag[((size_t)blockIdx.x * 64 + lane) * 3 + K] = frag;
    }
}

// ---------------- Phase A: conv via bf16 MFMA, one WAVE per edge, both etypes ----------------
// Swapped-operand GEMM per edge & row-pair y: D[x][m] (m=(sd,co)), K=96.
//   A (LDS)  : ef patch fragments — ds_read_b128
//   B (regs) : weight fragments (wprep)
//   D        : col m = lane&15, rows x = (lane>>4)*4+j -> f4 stores
// Gathers read the bf16-packed feats (8 KB/edge instead of 16 KB).
// Also writes m_e = bf16(u + Wh) at CSR slot pos[e] for the streaming mean.
__global__ __launch_bounds__(256, 4) void conv_kernel(
    const unsigned short* __restrict__ pa, const unsigned short* __restrict__ pb,
    const float* __restrict__ bias1, const float* __restrict__ bias2,
    const int* __restrict__ src1, const int* __restrict__ dst1,
    const int* __restrict__ src2, const int* __restrict__ dst2,
    const int* __restrict__ pos1, const int* __restrict__ pos2,
    const short8* __restrict__ wfrag,     // [2][64][3]
    float* __restrict__ Wh1, float* __restrict__ Wh2,
    unsigned short* __restrict__ m1, unsigned short* __restrict__ m2)
{
    __shared__ unsigned short lds[4 * TILE_US];   // 20.7 KB
    const int tid  = threadIdx.x;
    const int lane = tid & 63;
    const int widx = tid >> 6;
    unsigned short* tp = &lds[widx * TILE_US];

    const int gw  = blockIdx.x * 4 + widx;        // 0 .. 2*NE-1
    const int et2 = gw >= NE;
    const int e   = et2 ? gw - NE : gw;

    const unsigned short* feat_src = et2 ? pb : pa;
    const unsigned short* feat_dst = et2 ? pa : pb;
    const int s  = __builtin_amdgcn_readfirstlane((et2 ? src2 : src1)[e]);
    const int d  = __builtin_amdgcn_readfirstlane((et2 ? dst2 : dst1)[e]);
    const int pe = __builtin_amdgcn_readfirstlane((et2 ? pos2 : pos1)[e]);

    const int g = lane >> 4;
    const int x = lane & 15;

    // weight fragments (L2-hot) + bias + A-read offsets
    short8 bF[3];
    #pragma unroll
    for (int K = 0; K < 3; ++K) bF[K] = wfrag[((size_t)(et2 ? 64 : 0) + lane) * 3 + K];
    int boff[3];
    #pragma unroll
    for (int K = 0; K < 3; ++K) {
        const int pair = K * 4 + g;
        const int dy   = pair / 3 - 1;
        const int dx   = pair % 3;
        boff[K] = (dy + 1) * 18 + (x + dx);
    }
    const float bv = (et2 ? bias2 : bias1)[x & 7];
    f32x4 cb = {bv, bv, bv, bv};

    // zero tile (halo)
    const f4 z4 = {0.f, 0.f, 0.f, 0.f};
    #pragma unroll
    for (int i = 0; i < 6; ++i) {
        int c = lane + 64 * i;
        if (c < CELLS) *(f4*)&tp[c * 8] = z4;
    }

    // stage ef = bf16(u + v) from bf16 gathers: lane's 4 cells = (sy, sx..sx+3);
    // per ci the lane's data sits at ush4 slot ci*64 + lane.
    {
        const ush4* up = (const ush4*)(feat_src + (size_t)s * CHW);
        const ush4* vp = (const ush4*)(feat_dst + (size_t)d * CHW);
        const int sy = lane >> 2;
        const int sx = (lane & 3) * 4;
        short8 pk[4];
        #pragma unroll
        for (int ci = 0; ci < 8; ++ci) {
            ush4 ub = up[ci * 64 + lane];
            ush4 vb = vp[ci * 64 + lane];
            #pragma unroll
            for (int j = 0; j < 4; ++j)
                pk[j][ci] = (short)f2bf(bf2f(ub[j]) + bf2f(vb[j]));
        }
        #pragma unroll
        for (int mm = 0; mm < 4; ++mm) {
            const int cell = (sy + 1) * 18 + (sx + 1 + mm);
            *(short8*)&tp[cell * 8] = pk[mm];       // ds_write_b128
        }
    }
    // wave-private tile: program order + lgkmcnt suffice, no barrier

    const int co = x & 7, sd = x >> 3, xs = g * 4;
    float*          whp = (et2 ? Wh2 : Wh1) + (size_t)e * CHW;
    unsigned short* mp  = (et2 ? m2 : m1) + (size_t)pe * CHW;
    const ush4*     u2  = (const ush4*)(feat_src + (size_t)s * CHW);

    #pragma unroll
    for (int y = 0; y < 8; ++y) {
        f32x4 acc = cb;
        #pragma unroll
        for (int K = 0; K < 3; ++K) {
            short8 a8 = *(const short8*)&tp[(36 * y + boff[K]) * 8];  // ds_read_b128
            acc = __builtin_amdgcn_mfma_f32_16x16x32_bf16(a8, bF[K], acc, 0, 0, 0);
        }
        const int off = co * 256 + (2 * y + sd) * 16 + xs;
        f4 w4 = {acc[0], acc[1], acc[2], acc[3]};
        __builtin_nontemporal_store(w4, (f4*)&whp[off]);   // Wh streamed
        ush4 ub = u2[off >> 2];                            // L1-hot bf16 u
        ush4 m4 = {f2bf(bf2f(ub[0]) + w4.x), f2bf(bf2f(ub[1]) + w4.y),
                   f2bf(bf2f(ub[2]) + w4.z), f2bf(bf2f(ub[3]) + w4.w)};
        *(ush4*)&mp[off] = m4;                             // plain store -> L2/L3 for mean
    }
}

// ---------------- Phase B: segment mean, one WAVE per node, both etypes ----------------
__global__ __launch_bounds__(256) void mean_kernel(
    const unsigned short* __restrict__ m1, const unsigned short* __restrict__ m2,
    const int* __restrict__ row1, const int* __restrict__ row2,
    float* __restrict__ h_b, float* __restrict__ h_a)
{
    const int tid  = threadIdx.x;
    const int lane = tid & 63;
    const int gw   = blockIdx.x * 4 + (tid >> 6);   // 0 .. NB+NA-1
    const int et2  = gw >= NB;
    const int n    = et2 ? gw - NB : gw;

    const unsigned short* mb = et2 ? m2 : m1;
    const int* row = et2 ? row2 : row1;
    float* hp = (et2 ? h_a : h_b) + (size_t)n * CHW;

    const int beg = row[n], end = row[n + 1];

    float acc[32];
    #pragma unroll
    for (int j = 0; j < 32; ++j) acc[j] = 0.0f;

    for (int i = beg; i < end; ++i) {
        const ush8* mpr = (const ush8*)(mb + (size_t)i * CHW);
        #pragma unroll
        for (int q = 0; q < 4; ++q) {
            ush8 v = __builtin_nontemporal_load(&mpr[lane + 64 * q]);
            #pragma unroll
            for (int j = 0; j < 8; ++j)
                acc[q * 8 + j] += bf2f(v[j]);
        }
    }

    const float inv = end > beg ? 1.0f / (float)(end - beg) : 0.0f;
    #pragma unroll
    for (int q = 0; q < 4; ++q) {
        const int base = (lane + 64 * q) * 8;
        f4 o0 = {acc[q*8+0] * inv, acc[q*8+1] * inv, acc[q*8+2] * inv, acc[q*8+3] * inv};
        f4 o1 = {acc[q*8+4] * inv, acc[q*8+5] * inv, acc[q*8+6] * inv, acc[q*8+7] * inv};
        __builtin_nontemporal_store(o0, (f4*)&hp[base]);
        __builtin_nontemporal_store(o1, (f4*)&hp[base + 4]);
    }
}

extern "C" void kernel_launch(void* const* d_in, const int* in_sizes, int n_in,
                              void* d_out, int out_size, void* d_ws, size_t ws_size,
                              hipStream_t stream) {
    const float* feat_a = (const float*)d_in[0];
    const float* feat_b = (const float*)d_in[1];
    const float* W_e1   = (const float*)d_in[2];
    const float* b_e1   = (const float*)d_in[3];
    const float* W_e2   = (const float*)d_in[4];
    const float* b_e2   = (const float*)d_in[5];
    const int*   src_e1 = (const int*)d_in[6];
    const int*   dst_e1 = (const int*)d_in[7];
    const int*   src_e2 = (const int*)d_in[8];
    const int*   dst_e2 = (const int*)d_in[9];

    float* out = (float*)d_out;
    float* h_a = out;                                  // [NA, 2048]
    float* h_b = out + (size_t)NA * CHW;               // [NB, 2048]
    float* Wh1 = out + (size_t)(NA + NB) * CHW;        // [E, 2048]
    float* Wh2 = Wh1 + (size_t)NE * CHW;               // [E, 2048]

    // ---- workspace layout ----
    int* ws    = (int*)d_ws;
    int* cnt1  = ws;                  // [8192]
    int* row1  = cnt1 + NB;           // [8193]
    int* cur1  = row1 + NB + 1;       // [8192]
    int* pos1  = cur1 + NB;           // [NE]
    int* cnt2  = pos1 + NE;           // [8192]
    int* row2  = cnt2 + NA;           // [8193]
    int* cur2  = row2 + NA + 1;       // [8192]
    int* pos2  = cur2 + NA;           // [NE]
    short8* wfrag = (short8*)((char*)d_ws + (512 << 10));            // [2][64][3]
    unsigned short* m1 = (unsigned short*)((char*)d_ws + (1 << 20)); // [NE][2048] bf16
    unsigned short* m2 = m1 + (size_t)NE * CHW;                      // [NE][2048] bf16
    unsigned short* pa = m2 + (size_t)NE * CHW;                      // [NA][2048] bf16
    unsigned short* pb = pa + (size_t)NA * CHW;                      // [NB][2048] bf16

    // prepack feats to bf16 (halves all gather traffic)
    pack_kernel<<<2048, 256, 0, stream>>>(feat_a, feat_b, pa, pb);

    // CSR build + weight prep
    zero_two_kernel<<<32, 256, 0, stream>>>(cnt1, cnt2, 8192);
    hist_kernel<<<(2 * NE) / 256, 256, 0, stream>>>(dst_e1, dst_e2, cnt1, cnt2);
    scan_kernel<<<2, 256, 0, stream>>>(cnt1, row1, cur1, cnt2, row2, cur2);
    scatter_kernel<<<(2 * NE) / 256, 256, 0, stream>>>(dst_e1, dst_e2, cur1, cur2, pos1, pos2);
    wprep_kernel<<<2, 64, 0, stream>>>(W_e1, W_e2, wfrag);

    // Phase A: conv for BOTH etypes in one dispatch (wave per edge)
    conv_kernel<<<(2 * NE) / 4, 256, 0, stream>>>(
        pa, pb, b_e1, b_e2,
        src_e1, dst_e1, src_e2, dst_e2,
        pos1, pos2, wfrag, Wh1, Wh2, m1, m2);

    // Phase B: segment mean for both etypes (wave per node)
    mean_kernel<<<(NB + NA) / 4, 256, 0, stream>>>(m1, m2, row1, row2, h_b, h_a);
}

// Round 13
// 205.893 us; speedup vs baseline: 2.3794x; 1.5691x over previous
//
#include <hip/hip_runtime.h>
#include <hip/hip_bf16.h>

#define NA 8192
#define NB 8192
#define NE 32768
#define NC 8
#define CHW 2048        // 8*16*16

typedef float          f4     __attribute__((ext_vector_type(4)));
typedef float          f32x4  __attribute__((ext_vector_type(4)));
typedef short          short8 __attribute__((ext_vector_type(8)));
typedef unsigned short ush4   __attribute__((ext_vector_type(4)));

// conv LDS tile: [18 rows][18 cols][8 ci] bf16; rows/cols 0,17 = zero halo;
// ci innermost -> one spatial point's 8-ci fragment is ONE ds_read_b128.
#define CELLS (18 * 18)
#define TILE_US (CELLS * 8)      // 5184 B per wave tile

static __device__ __forceinline__ unsigned short f2bf(float f) {
    __hip_bfloat16 h = __float2bfloat16(f);
    return __builtin_bit_cast(unsigned short, h);
}
static __device__ __forceinline__ float bf2f(unsigned short u) {
    return __uint_as_float(((unsigned)u) << 16);
}

// ---------------- bf16 prepack of both feature arrays ----------------
__global__ __launch_bounds__(256) void pack_kernel(
    const float* __restrict__ fa, const float* __restrict__ fb,
    unsigned short* __restrict__ ga, unsigned short* __restrict__ gb)
{
    const size_t n4 = (size_t)NA * CHW / 4;
    size_t stride = (size_t)gridDim.x * 256;
    for (size_t i = (size_t)blockIdx.x * 256 + threadIdx.x; i < n4; i += stride) {
        f4 va = ((const f4*)fa)[i];
        f4 vb = ((const f4*)fb)[i];
        ush4 oa = {f2bf(va.x), f2bf(va.y), f2bf(va.z), f2bf(va.w)};
        ush4 ob = {f2bf(vb.x), f2bf(vb.y), f2bf(vb.z), f2bf(vb.w)};
        ((ush4*)ga)[i] = oa;
        ((ush4*)gb)[i] = ob;
    }
}

// ---------------- CSR build ----------------
__global__ __launch_bounds__(256) void zero_two_kernel(int* a, int* b, int n) {
    int i = blockIdx.x * 256 + threadIdx.x;
    if (i < n) { a[i] = 0; b[i] = 0; }
}

__global__ __launch_bounds__(256) void hist_kernel(
    const int* __restrict__ dst1, const int* __restrict__ dst2,
    int* __restrict__ cnt1, int* __restrict__ cnt2) {
    int i = blockIdx.x * 256 + threadIdx.x;   // grid covers 2*NE
    if (i < NE) atomicAdd(&cnt1[dst1[i]], 1);
    else        atomicAdd(&cnt2[dst2[i - NE]], 1);
}

__global__ __launch_bounds__(256) void scan_kernel(
    const int* __restrict__ cnt1, int* __restrict__ row1, int* __restrict__ cur1,
    const int* __restrict__ cnt2, int* __restrict__ row2, int* __restrict__ cur2) {
    const int n = 8192;
    const int* cnt = blockIdx.x ? cnt2 : cnt1;
    int* row = blockIdx.x ? row2 : row1;
    int* cur = blockIdx.x ? cur2 : cur1;
    __shared__ int part[256];
    const int t = threadIdx.x;
    const int chunk = n / 256;
    const int base = t * chunk;
    int sum = 0;
    for (int j = 0; j < chunk; ++j) sum += cnt[base + j];
    part[t] = sum;
    __syncthreads();
    if (t == 0) {
        int run = 0;
        for (int i = 0; i < 256; ++i) { int tmp = part[i]; part[i] = run; run += tmp; }
    }
    __syncthreads();
    int run = part[t];
    for (int j = 0; j < chunk; ++j) {
        row[base + j] = run; cur[base + j] = run; run += cnt[base + j];
    }
    if (t == 255) row[n] = run;
}

// perm: edge ids grouped by dst (CSR order)
__global__ __launch_bounds__(256) void scatter_kernel(
    const int* __restrict__ dst1, const int* __restrict__ dst2,
    int* __restrict__ cur1, int* __restrict__ cur2,
    int* __restrict__ perm1, int* __restrict__ perm2) {
    int i = blockIdx.x * 256 + threadIdx.x;   // grid covers 2*NE
    if (i < NE)  { int p = atomicAdd(&cur1[dst1[i]], 1);      perm1[p] = i; }
    else         { int p = atomicAdd(&cur2[dst2[i - NE]], 1); perm2[p] = i - NE; }
}

// ---------------- weight-fragment prep ----------------
__global__ __launch_bounds__(64) void wprep_kernel(
    const float* __restrict__ W1, const float* __restrict__ W2,
    short8* __restrict__ wfrag)           // [2][64][3]
{
    const float* Wc = blockIdx.x ? W2 : W1;
    const int lane = threadIdx.x;
    const int nn = lane & 15;
    const int sd = nn >> 3, co = nn & 7;
    #pragma unroll
    for (int K = 0; K < 3; ++K) {
        short8 frag;
        #pragma unroll
        for (int j = 0; j < 8; ++j) {
            const int k    = K * 32 + (lane >> 4) * 8 + j;
            const int pair = k >> 3;
            const int dy   = pair / 3 - 1;
            const int dx   = pair % 3;
            const int ci   = k & 7;
            const int ky   = dy - sd + 1;
            float w = (ky >= 0 && ky <= 2) ? Wc[((co * 8 + ci) * 3 + ky) * 3 + dx] : 0.0f;
            frag[j] = (short)f2bf(w);
        }
        wfrag[((size_t)blockIdx.x * 64 + lane) * 3 + K] = frag;
    }
}

// ---------------- fused conv + aggregate: one WAVE per dst node ----------------
// v loaded to regs once per node; per edge: gather u (bf16, prefetched), stage
// ef=u+v, 24 MFMA -> Wh nt-store, macc += u + Wh (regs). h = macc/deg, once.
// No m intermediate, no mean pass, no atomics.
__global__ __launch_bounds__(256, 3) void conv_node_kernel(
    const unsigned short* __restrict__ pa, const unsigned short* __restrict__ pb,
    const float* __restrict__ bias1, const float* __restrict__ bias2,
    const int* __restrict__ src1, const int* __restrict__ src2,
    const int* __restrict__ row1, const int* __restrict__ row2,
    const int* __restrict__ perm1, const int* __restrict__ perm2,
    const short8* __restrict__ wfrag,     // [2][64][3]
    float* __restrict__ Wh1, float* __restrict__ Wh2,
    float* __restrict__ h_b, float* __restrict__ h_a)
{
    __shared__ unsigned short lds[4 * TILE_US];   // 20.7 KB
    const int tid  = threadIdx.x;
    const int lane = tid & 63;
    const int widx = tid >> 6;
    unsigned short* tp = &lds[widx * TILE_US];

    const int gw  = blockIdx.x * 4 + widx;        // 0 .. NB+NA-1
    const int et2 = gw >= NB;
    const int n   = et2 ? gw - NB : gw;           // dst node id

    const unsigned short* feat_src = et2 ? pb : pa;
    const unsigned short* feat_dst = et2 ? pa : pb;
    const int* srcp = et2 ? src2 : src1;
    const int* rowp = et2 ? row2 : row1;
    const int* prmp = et2 ? perm2 : perm1;
    float*     Whp  = et2 ? Wh2 : Wh1;
    float*     hout = et2 ? h_a : h_b;            // e1: dst in b; e2: dst in a

    const int g = lane >> 4;
    const int x = lane & 15;

    // weight fragments + bias + A-read offsets
    short8 bF[3];
    #pragma unroll
    for (int K = 0; K < 3; ++K) bF[K] = wfrag[((size_t)(et2 ? 64 : 0) + lane) * 3 + K];
    int boff[3];
    #pragma unroll
    for (int K = 0; K < 3; ++K) {
        const int pair = K * 4 + g;
        const int dy   = pair / 3 - 1;
        const int dx   = pair % 3;
        boff[K] = (dy + 1) * 18 + (x + dx);
    }
    const float bv = (et2 ? bias2 : bias1)[x & 7];
    f32x4 cb = {bv, bv, bv, bv};

    // zero tile (halo)
    const f4 z4 = {0.f, 0.f, 0.f, 0.f};
    #pragma unroll
    for (int i = 0; i < 6; ++i) {
        int c = lane + 64 * i;
        if (c < CELLS) *(f4*)&tp[c * 8] = z4;
    }

    const int beg = __builtin_amdgcn_readfirstlane(rowp[n]);
    const int end = __builtin_amdgcn_readfirstlane(rowp[n + 1]);

    // v (dst feature) -> registers, once per node
    ush4 vb[8];
    {
        const ush4* vp = (const ush4*)(feat_dst + (size_t)n * CHW);
        #pragma unroll
        for (int ci = 0; ci < 8; ++ci) vb[ci] = vp[ci * 64 + lane];
    }

    const int co = x & 7, sd = x >> 3, xs = g * 4;

    // m accumulator: lane's 32 output values (8 y-pairs x f4)
    f4 macc[8];
    #pragma unroll
    for (int y = 0; y < 8; ++y) macc[y] = z4;

    // prologue: prefetch first edge's u and src base
    int eN = 0, sN = 0;
    ush4 ub[8];
    if (beg < end) {
        eN = __builtin_amdgcn_readfirstlane(prmp[beg]);
        sN = __builtin_amdgcn_readfirstlane(srcp[eN]);
        const ush4* up = (const ush4*)(feat_src + (size_t)sN * CHW);
        #pragma unroll
        for (int ci = 0; ci < 8; ++ci) ub[ci] = up[ci * 64 + lane];
    }

    for (int i = beg; i < end; ++i) {
        const int e = eN, s = sN;
        ush4 uc[8];
        #pragma unroll
        for (int ci = 0; ci < 8; ++ci) uc[ci] = ub[ci];

        // prefetch next edge's u (hides gather latency under MFMA + stores)
        if (i + 1 < end) {
            eN = __builtin_amdgcn_readfirstlane(prmp[i + 1]);
            sN = __builtin_amdgcn_readfirstlane(srcp[eN]);
            const ush4* up = (const ush4*)(feat_src + (size_t)sN * CHW);
            #pragma unroll
            for (int ci = 0; ci < 8; ++ci) ub[ci] = up[ci * 64 + lane];
        }

        // stage ef = bf16(u + v): lane's 4 cells = (sy, sx..sx+3)
        {
            const int sy = lane >> 2;
            const int sx = (lane & 3) * 4;
            short8 pk[4];
            #pragma unroll
            for (int ci = 0; ci < 8; ++ci) {
                #pragma unroll
                for (int j = 0; j < 4; ++j)
                    pk[j][ci] = (short)f2bf(bf2f(uc[ci][j]) + bf2f(vb[ci][j]));
            }
            #pragma unroll
            for (int mm = 0; mm < 4; ++mm) {
                const int cell = (sy + 1) * 18 + (sx + 1 + mm);
                *(short8*)&tp[cell * 8] = pk[mm];       // ds_write_b128
            }
        }
        // wave-private tile: program order + lgkmcnt, no barrier

        // 8 row-pair MFMA triplets; Wh nt-store; macc += u + Wh
        float* whp = Whp + (size_t)e * CHW;
        const ush4* u2 = (const ush4*)(feat_src + (size_t)s * CHW);
        #pragma unroll
        for (int y = 0; y < 8; ++y) {
            f32x4 acc = cb;
            #pragma unroll
            for (int K = 0; K < 3; ++K) {
                short8 a8 = *(const short8*)&tp[(36 * y + boff[K]) * 8];  // ds_read_b128
                acc = __builtin_amdgcn_mfma_f32_16x16x32_bf16(a8, bF[K], acc, 0, 0, 0);
            }
            const int off = co * 256 + (2 * y + sd) * 16 + xs;
            f4 w4 = {acc[0], acc[1], acc[2], acc[3]};
            __builtin_nontemporal_store(w4, (f4*)&whp[off]);   // Wh streamed
            ush4 u4 = u2[off >> 2];                            // L1-hot bf16 u
            f4 mv = {bf2f(u4[0]) + w4.x, bf2f(u4[1]) + w4.y,
                     bf2f(u4[2]) + w4.z, bf2f(u4[3]) + w4.w};
            macc[y] += mv;
        }
    }

    // h = mean (deg==0 -> zeros, matching DGL)
    const int deg = end - beg;
    const float inv = deg > 0 ? 1.0f / (float)deg : 0.0f;
    float* hp = hout + (size_t)n * CHW;
    #pragma unroll
    for (int y = 0; y < 8; ++y) {
        const int off = co * 256 + (2 * y + sd) * 16 + xs;
        f4 o = macc[y] * inv;
        __builtin_nontemporal_store(o, (f4*)&hp[off]);
    }
}

extern "C" void kernel_launch(void* const* d_in, const int* in_sizes, int n_in,
                              void* d_out, int out_size, void* d_ws, size_t ws_size,
                              hipStream_t stream) {
    const float* feat_a = (const float*)d_in[0];
    const float* feat_b = (const float*)d_in[1];
    const float* W_e1   = (const float*)d_in[2];
    const float* b_e1   = (const float*)d_in[3];
    const float* W_e2   = (const float*)d_in[4];
    const float* b_e2   = (const float*)d_in[5];
    const int*   src_e1 = (const int*)d_in[6];
    const int*   dst_e1 = (const int*)d_in[7];
    const int*   src_e2 = (const int*)d_in[8];
    const int*   dst_e2 = (const int*)d_in[9];

    float* out = (float*)d_out;
    float* h_a = out;                                  // [NA, 2048]
    float* h_b = out + (size_t)NA * CHW;               // [NB, 2048]
    float* Wh1 = out + (size_t)(NA + NB) * CHW;        // [E, 2048]
    float* Wh2 = Wh1 + (size_t)NE * CHW;               // [E, 2048]

    // ---- workspace ----
    int* ws    = (int*)d_ws;
    int* cnt1  = ws;                  // [8192]
    int* row1  = cnt1 + NB;           // [8193]
    int* cur1  = row1 + NB + 1;       // [8192]
    int* perm1 = cur1 + NB;           // [NE]
    int* cnt2  = perm1 + NE;          // [8192]
    int* row2  = cnt2 + NA;           // [8193]
    int* cur2  = row2 + NA + 1;       // [8192]
    int* perm2 = cur2 + NA;           // [NE]
    short8* wfrag = (short8*)((char*)d_ws + (512 << 10));            // [2][64][3]
    unsigned short* pa = (unsigned short*)((char*)d_ws + (1 << 20)); // [NA][2048] bf16
    unsigned short* pb = pa + (size_t)NA * CHW;                      // [NB][2048] bf16

    // prepack feats to bf16 (halves gather traffic)
    pack_kernel<<<2048, 256, 0, stream>>>(feat_a, feat_b, pa, pb);

    // CSR build + weight prep
    zero_two_kernel<<<32, 256, 0, stream>>>(cnt1, cnt2, 8192);
    hist_kernel<<<(2 * NE) / 256, 256, 0, stream>>>(dst_e1, dst_e2, cnt1, cnt2);
    scan_kernel<<<2, 256, 0, stream>>>(cnt1, row1, cur1, cnt2, row2, cur2);
    scatter_kernel<<<(2 * NE) / 256, 256, 0, stream>>>(dst_e1, dst_e2, cur1, cur2, perm1, perm2);
    wprep_kernel<<<2, 64, 0, stream>>>(W_e1, W_e2, wfrag);

    // fused conv + segment-mean: one dispatch, wave per dst node, both etypes
    conv_node_kernel<<<(NB + NA) / 4, 256, 0, stream>>>(
        pa, pb, b_e1, b_e2, src_e1, src_e2,
        row1, row2, perm1, perm2, wfrag, Wh1, Wh2, h_b, h_a);
}

// Round 14
// 201.689 us; speedup vs baseline: 2.4290x; 1.0208x over previous
//
#include <hip/hip_runtime.h>
#include <hip/hip_bf16.h>

#define NA 8192
#define NB 8192
#define NE 32768
#define NC 8
#define CHW 2048        // 8*16*16

typedef float          f4     __attribute__((ext_vector_type(4)));
typedef float          f32x4  __attribute__((ext_vector_type(4)));
typedef short          short8 __attribute__((ext_vector_type(8)));
typedef unsigned short ush4   __attribute__((ext_vector_type(4)));
typedef int            i4v    __attribute__((ext_vector_type(4)));

// conv LDS tile: [18 rows][18 cols][8 ci] bf16; rows/cols 0,17 = zero halo;
// ci innermost -> one spatial point's 8-ci fragment is ONE ds_read_b128.
#define CELLS (18 * 18)
#define TILE_US (CELLS * 8)      // 5184 B per wave tile

static __device__ __forceinline__ unsigned short f2bf(float f) {
    __hip_bfloat16 h = __float2bfloat16(f);
    return __builtin_bit_cast(unsigned short, h);
}
static __device__ __forceinline__ float bf2f(unsigned short u) {
    return __uint_as_float(((unsigned)u) << 16);
}

// ---------------- prep: weight fragments (blocks 0,1) + zero counts (block 2) ----------------
__global__ __launch_bounds__(256) void prep_kernel(
    const float* __restrict__ W1, const float* __restrict__ W2,
    short8* __restrict__ wfrag,           // [2][64][3]
    int* __restrict__ cnt1, int* __restrict__ cnt2)
{
    if (blockIdx.x == 2) {                // zero cnt1 + cnt2 (8192 ints each)
        const i4v z = {0, 0, 0, 0};
        for (int i = threadIdx.x; i < 2048; i += 256) {
            ((i4v*)cnt1)[i] = z;
            ((i4v*)cnt2)[i] = z;
        }
        return;
    }
    if (threadIdx.x >= 64) return;
    const float* Wc = blockIdx.x ? W2 : W1;
    const int lane = threadIdx.x;
    const int nn = lane & 15;
    const int sd = nn >> 3, co = nn & 7;
    #pragma unroll
    for (int K = 0; K < 3; ++K) {
        short8 frag;
        #pragma unroll
        for (int j = 0; j < 8; ++j) {
            const int k    = K * 32 + (lane >> 4) * 8 + j;
            const int pair = k >> 3;
            const int dy   = pair / 3 - 1;
            const int dx   = pair % 3;
            const int ci   = k & 7;
            const int ky   = dy - sd + 1;
            float w = (ky >= 0 && ky <= 2) ? Wc[((co * 8 + ci) * 3 + ky) * 3 + dx] : 0.0f;
            frag[j] = (short)f2bf(w);
        }
        wfrag[((size_t)blockIdx.x * 64 + lane) * 3 + K] = frag;
    }
}

// ---------------- pack (blocks 0..2047) ∥ hist (blocks 2048..2303) ----------------
__global__ __launch_bounds__(256) void packhist_kernel(
    const float* __restrict__ fa, const float* __restrict__ fb,
    unsigned short* __restrict__ ga, unsigned short* __restrict__ gb,
    const int* __restrict__ dst1, const int* __restrict__ dst2,
    int* __restrict__ cnt1, int* __restrict__ cnt2)
{
    if (blockIdx.x < 2048) {              // bf16 prepack of both feature arrays
        const size_t n4 = (size_t)NA * CHW / 4;
        const size_t stride = (size_t)2048 * 256;
        for (size_t i = (size_t)blockIdx.x * 256 + threadIdx.x; i < n4; i += stride) {
            f4 va = ((const f4*)fa)[i];
            f4 vb = ((const f4*)fb)[i];
            ush4 oa = {f2bf(va.x), f2bf(va.y), f2bf(va.z), f2bf(va.w)};
            ush4 ob = {f2bf(vb.x), f2bf(vb.y), f2bf(vb.z), f2bf(vb.w)};
            ((ush4*)ga)[i] = oa;
            ((ush4*)gb)[i] = ob;
        }
    } else {                              // in-degree histograms (2*NE threads)
        int i = (blockIdx.x - 2048) * 256 + threadIdx.x;
        if (i < NE) atomicAdd(&cnt1[dst1[i]], 1);
        else        atomicAdd(&cnt2[dst2[i - NE]], 1);
    }
}

// ---------------- CSR scan + scatter ----------------
__global__ __launch_bounds__(256) void scan_kernel(
    const int* __restrict__ cnt1, int* __restrict__ row1, int* __restrict__ cur1,
    const int* __restrict__ cnt2, int* __restrict__ row2, int* __restrict__ cur2) {
    const int n = 8192;
    const int* cnt = blockIdx.x ? cnt2 : cnt1;
    int* row = blockIdx.x ? row2 : row1;
    int* cur = blockIdx.x ? cur2 : cur1;
    __shared__ int part[256];
    const int t = threadIdx.x;
    const int chunk = n / 256;
    const int base = t * chunk;
    int sum = 0;
    for (int j = 0; j < chunk; ++j) sum += cnt[base + j];
    part[t] = sum;
    __syncthreads();
    if (t == 0) {
        int run = 0;
        for (int i = 0; i < 256; ++i) { int tmp = part[i]; part[i] = run; run += tmp; }
    }
    __syncthreads();
    int run = part[t];
    for (int j = 0; j < chunk; ++j) {
        row[base + j] = run; cur[base + j] = run; run += cnt[base + j];
    }
    if (t == 255) row[n] = run;
}

__global__ __launch_bounds__(256) void scatter_kernel(
    const int* __restrict__ dst1, const int* __restrict__ dst2,
    int* __restrict__ cur1, int* __restrict__ cur2,
    int* __restrict__ perm1, int* __restrict__ perm2) {
    int i = blockIdx.x * 256 + threadIdx.x;   // grid covers 2*NE
    if (i < NE)  { int p = atomicAdd(&cur1[dst1[i]], 1);      perm1[p] = i; }
    else         { int p = atomicAdd(&cur2[dst2[i - NE]], 1); perm2[p] = i - NE; }
}

// ---------------- fused conv + aggregate: one WAVE per dst node ----------------
// v loaded to regs once per node; per edge: gather u (bf16, prefetched), stage
// ef=u+v, 24 MFMA -> Wh nt-store, macc += u + Wh (regs). h = macc/deg, once.
__global__ __launch_bounds__(256, 3) void conv_node_kernel(
    const unsigned short* __restrict__ pa, const unsigned short* __restrict__ pb,
    const float* __restrict__ bias1, const float* __restrict__ bias2,
    const int* __restrict__ src1, const int* __restrict__ src2,
    const int* __restrict__ row1, const int* __restrict__ row2,
    const int* __restrict__ perm1, const int* __restrict__ perm2,
    const short8* __restrict__ wfrag,     // [2][64][3]
    float* __restrict__ Wh1, float* __restrict__ Wh2,
    float* __restrict__ h_b, float* __restrict__ h_a)
{
    __shared__ unsigned short lds[4 * TILE_US];   // 20.7 KB
    const int tid  = threadIdx.x;
    const int lane = tid & 63;
    const int widx = tid >> 6;
    unsigned short* tp = &lds[widx * TILE_US];

    const int gw  = blockIdx.x * 4 + widx;        // 0 .. NB+NA-1
    const int et2 = gw >= NB;
    const int n   = et2 ? gw - NB : gw;           // dst node id

    const unsigned short* feat_src = et2 ? pb : pa;
    const unsigned short* feat_dst = et2 ? pa : pb;
    const int* srcp = et2 ? src2 : src1;
    const int* rowp = et2 ? row2 : row1;
    const int* prmp = et2 ? perm2 : perm1;
    float*     Whp  = et2 ? Wh2 : Wh1;
    float*     hout = et2 ? h_a : h_b;            // e1: dst in b; e2: dst in a

    const int g = lane >> 4;
    const int x = lane & 15;

    // weight fragments + bias + A-read offsets
    short8 bF[3];
    #pragma unroll
    for (int K = 0; K < 3; ++K) bF[K] = wfrag[((size_t)(et2 ? 64 : 0) + lane) * 3 + K];
    int boff[3];
    #pragma unroll
    for (int K = 0; K < 3; ++K) {
        const int pair = K * 4 + g;
        const int dy   = pair / 3 - 1;
        const int dx   = pair % 3;
        boff[K] = (dy + 1) * 18 + (x + dx);
    }
    const float bv = (et2 ? bias2 : bias1)[x & 7];
    f32x4 cb = {bv, bv, bv, bv};

    // zero tile (halo)
    const f4 z4 = {0.f, 0.f, 0.f, 0.f};
    #pragma unroll
    for (int i = 0; i < 6; ++i) {
        int c = lane + 64 * i;
        if (c < CELLS) *(f4*)&tp[c * 8] = z4;
    }

    const int beg = __builtin_amdgcn_readfirstlane(rowp[n]);
    const int end = __builtin_amdgcn_readfirstlane(rowp[n + 1]);

    // v (dst feature) -> registers, once per node
    ush4 vb[8];
    {
        const ush4* vp = (const ush4*)(feat_dst + (size_t)n * CHW);
        #pragma unroll
        for (int ci = 0; ci < 8; ++ci) vb[ci] = vp[ci * 64 + lane];
    }

    const int co = x & 7, sd = x >> 3, xs = g * 4;

    // m accumulator: lane's 32 output values (8 y-pairs x f4)
    f4 macc[8];
    #pragma unroll
    for (int y = 0; y < 8; ++y) macc[y] = z4;

    // prologue: prefetch first edge's u and src base
    int eN = 0, sN = 0;
    ush4 ub[8];
    if (beg < end) {
        eN = __builtin_amdgcn_readfirstlane(prmp[beg]);
        sN = __builtin_amdgcn_readfirstlane(srcp[eN]);
        const ush4* up = (const ush4*)(feat_src + (size_t)sN * CHW);
        #pragma unroll
        for (int ci = 0; ci < 8; ++ci) ub[ci] = up[ci * 64 + lane];
    }

    for (int i = beg; i < end; ++i) {
        const int e = eN, s = sN;
        ush4 uc[8];
        #pragma unroll
        for (int ci = 0; ci < 8; ++ci) uc[ci] = ub[ci];

        // prefetch next edge's u (hides gather latency under MFMA + stores)
        if (i + 1 < end) {
            eN = __builtin_amdgcn_readfirstlane(prmp[i + 1]);
            sN = __builtin_amdgcn_readfirstlane(srcp[eN]);
            const ush4* up = (const ush4*)(feat_src + (size_t)sN * CHW);
            #pragma unroll
            for (int ci = 0; ci < 8; ++ci) ub[ci] = up[ci * 64 + lane];
        }

        // stage ef = bf16(u + v): lane's 4 cells = (sy, sx..sx+3)
        {
            const int sy = lane >> 2;
            const int sx = (lane & 3) * 4;
            short8 pk[4];
            #pragma unroll
            for (int ci = 0; ci < 8; ++ci) {
                #pragma unroll
                for (int j = 0; j < 4; ++j)
                    pk[j][ci] = (short)f2bf(bf2f(uc[ci][j]) + bf2f(vb[ci][j]));
            }
            #pragma unroll
            for (int mm = 0; mm < 4; ++mm) {
                const int cell = (sy + 1) * 18 + (sx + 1 + mm);
                *(short8*)&tp[cell * 8] = pk[mm];       // ds_write_b128
            }
        }
        // wave-private tile: program order + lgkmcnt, no barrier

        // 8 row-pair MFMA triplets; Wh nt-store; macc += u + Wh
        float* whp = Whp + (size_t)e * CHW;
        const ush4* u2 = (const ush4*)(feat_src + (size_t)s * CHW);
        #pragma unroll
        for (int y = 0; y < 8; ++y) {
            f32x4 acc = cb;
            #pragma unroll
            for (int K = 0; K < 3; ++K) {
                short8 a8 = *(const short8*)&tp[(36 * y + boff[K]) * 8];  // ds_read_b128
                acc = __builtin_amdgcn_mfma_f32_16x16x32_bf16(a8, bF[K], acc, 0, 0, 0);
            }
            const int off = co * 256 + (2 * y + sd) * 16 + xs;
            f4 w4 = {acc[0], acc[1], acc[2], acc[3]};
            __builtin_nontemporal_store(w4, (f4*)&whp[off]);   // Wh streamed
            ush4 u4 = u2[off >> 2];                            // L1-hot bf16 u
            f4 mv = {bf2f(u4[0]) + w4.x, bf2f(u4[1]) + w4.y,
                     bf2f(u4[2]) + w4.z, bf2f(u4[3]) + w4.w};
            macc[y] += mv;
        }
    }

    // h = mean (deg==0 -> zeros, matching DGL)
    const int deg = end - beg;
    const float inv = deg > 0 ? 1.0f / (float)deg : 0.0f;
    float* hp = hout + (size_t)n * CHW;
    #pragma unroll
    for (int y = 0; y < 8; ++y) {
        const int off = co * 256 + (2 * y + sd) * 16 + xs;
        f4 o = macc[y] * inv;
        __builtin_nontemporal_store(o, (f4*)&hp[off]);
    }
}

extern "C" void kernel_launch(void* const* d_in, const int* in_sizes, int n_in,
                              void* d_out, int out_size, void* d_ws, size_t ws_size,
                              hipStream_t stream) {
    const float* feat_a = (const float*)d_in[0];
    const float* feat_b = (const float*)d_in[1];
    const float* W_e1   = (const float*)d_in[2];
    const float* b_e1   = (const float*)d_in[3];
    const float* W_e2   = (const float*)d_in[4];
    const float* b_e2   = (const float*)d_in[5];
    const int*   src_e1 = (const int*)d_in[6];
    const int*   dst_e1 = (const int*)d_in[7];
    const int*   src_e2 = (const int*)d_in[8];
    const int*   dst_e2 = (const int*)d_in[9];

    float* out = (float*)d_out;
    float* h_a = out;                                  // [NA, 2048]
    float* h_b = out + (size_t)NA * CHW;               // [NB, 2048]
    float* Wh1 = out + (size_t)(NA + NB) * CHW;        // [E, 2048]
    float* Wh2 = Wh1 + (size_t)NE * CHW;               // [E, 2048]

    // ---- workspace ----
    int* ws    = (int*)d_ws;
    int* cnt1  = ws;                  // [8192]
    int* row1  = cnt1 + NB;           // [8193]
    int* cur1  = row1 + NB + 1;       // [8192]
    int* perm1 = cur1 + NB;           // [NE]
    int* cnt2  = perm1 + NE;          // [8192]
    int* row2  = cnt2 + NA;           // [8193]
    int* cur2  = row2 + NA + 1;       // [8192]
    int* perm2 = cur2 + NA;           // [NE]
    short8* wfrag = (short8*)((char*)d_ws + (512 << 10));            // [2][64][3]
    unsigned short* pa = (unsigned short*)((char*)d_ws + (1 << 20)); // [NA][2048] bf16
    unsigned short* pb = pa + (size_t)NA * CHW;                      // [NB][2048] bf16

    // 4-dispatch pre-chain: prep -> pack||hist -> scan -> scatter
    prep_kernel<<<3, 256, 0, stream>>>(W_e1, W_e2, wfrag, cnt1, cnt2);
    packhist_kernel<<<2048 + 256, 256, 0, stream>>>(feat_a, feat_b, pa, pb,
                                                    dst_e1, dst_e2, cnt1, cnt2);
    scan_kernel<<<2, 256, 0, stream>>>(cnt1, row1, cur1, cnt2, row2, cur2);
    scatter_kernel<<<(2 * NE) / 256, 256, 0, stream>>>(dst_e1, dst_e2, cur1, cur2, perm1, perm2);

    // fused conv + segment-mean: one dispatch, wave per dst node, both etypes
    conv_node_kernel<<<(NB + NA) / 4, 256, 0, stream>>>(
        pa, pb, b_e1, b_e2, src_e1, src_e2,
        row1, row2, perm1, perm2, wfrag, Wh1, Wh2, h_b, h_a);
}